// Round 1
// baseline (238.221 us; speedup 1.0000x reference)
//
#include <hip/hip_runtime.h>
#include <hip/hip_bf16.h>

// MHA forward: B=4, S=1024, D=1024, H=16, DK=64.
// Pipeline: 3 proj GEMMs (f32 in -> bf16 out, V stored head-transposed),
// fused attention (scores in regs, softmax, PV), final proj GEMM (f32 out).

typedef __bf16 bf16x8 __attribute__((ext_vector_type(8)));
typedef float f32x4 __attribute__((ext_vector_type(4)));
typedef unsigned short us8 __attribute__((ext_vector_type(8)));
typedef unsigned short us4 __attribute__((ext_vector_type(4)));

#define MFMA(a, b, c) __builtin_amdgcn_mfma_f32_16x16x32_bf16(a, b, c, 0, 0, 0)

__device__ __forceinline__ unsigned short f2bf(float f) {
  unsigned u = __builtin_bit_cast(unsigned, f);
  u += 0x7fffu + ((u >> 16) & 1u);   // RNE
  return (unsigned short)(u >> 16);
}

__device__ __forceinline__ bf16x8 ldbf8(const unsigned short* p) {
  return __builtin_bit_cast(bf16x8, *reinterpret_cast<const us8*>(p));
}

// stage 8 elements into LDS (convert f32->bf16 on the fly, or raw bf16 copy)
__device__ __forceinline__ void stage8(unsigned short* d, const float* g) {
  const float4* p = reinterpret_cast<const float4*>(g);
  float4 x = p[0], y = p[1];
  us8 o;
  o[0] = f2bf(x.x); o[1] = f2bf(x.y); o[2] = f2bf(x.z); o[3] = f2bf(x.w);
  o[4] = f2bf(y.x); o[5] = f2bf(y.y); o[6] = f2bf(y.z); o[7] = f2bf(y.w);
  *reinterpret_cast<us8*>(d) = o;
}
__device__ __forceinline__ void stage8(unsigned short* d, const unsigned short* g) {
  *reinterpret_cast<us8*>(d) = *reinterpret_cast<const us8*>(g);
}

// C[m][n] = sum_k A[m][k] * Bw[n][k] + bias[n]   (NT GEMM, M=4096, N=K=1024)
// OUTMODE: 0 = bf16 [M][N], 1 = f32 [M][N], 2 = bf16 head-transposed Vt[bh][d][s]
template <typename AT, int OUTMODE>
__global__ __launch_bounds__(256)
void gemm_nt(const AT* __restrict__ A, const float* __restrict__ Bw,
             const float* __restrict__ bias, void* __restrict__ OutP) {
  constexpr int K = 1024, N = 1024;
  __shared__ unsigned short As[64][72];  // 64 + 8 pad: conflict-free ds_read_b128
  __shared__ unsigned short Bs[64][72];
  const int bm = blockIdx.x * 64, bn = blockIdx.y * 64;
  const int t = threadIdx.x;
  const int wave = t >> 6, lane = t & 63, lr = lane & 15, lg = lane >> 4;
  const int srow = t >> 2, scol = (t & 3) * 8;

  f32x4 acc[4];
#pragma unroll
  for (int i = 0; i < 4; ++i) acc[i] = f32x4{0.f, 0.f, 0.f, 0.f};

  for (int k0 = 0; k0 < K; k0 += 64) {
    stage8(&As[srow][scol],      A  + (size_t)(bm + srow) * K + k0 + scol);
    stage8(&As[srow][scol + 32], A  + (size_t)(bm + srow) * K + k0 + scol + 32);
    stage8(&Bs[srow][scol],      Bw + (size_t)(bn + srow) * K + k0 + scol);
    stage8(&Bs[srow][scol + 32], Bw + (size_t)(bn + srow) * K + k0 + scol + 32);
    __syncthreads();
    bf16x8 a0 = ldbf8(&As[wave * 16 + lr][lg * 8]);
    bf16x8 a1 = ldbf8(&As[wave * 16 + lr][32 + lg * 8]);
#pragma unroll
    for (int nt = 0; nt < 4; ++nt) {
      bf16x8 b0 = ldbf8(&Bs[nt * 16 + lr][lg * 8]);
      bf16x8 b1 = ldbf8(&Bs[nt * 16 + lr][32 + lg * 8]);
      acc[nt] = MFMA(a0, b0, acc[nt]);
      acc[nt] = MFMA(a1, b1, acc[nt]);
    }
    __syncthreads();
  }

  const int m0 = bm + wave * 16 + lg * 4;  // 4 consecutive output rows per lane
#pragma unroll
  for (int nt = 0; nt < 4; ++nt) {
    const int n = bn + nt * 16 + lr;
    const float bb = bias[n];
    if constexpr (OUTMODE == 0) {
      unsigned short* o = (unsigned short*)OutP;
#pragma unroll
      for (int r = 0; r < 4; ++r)
        o[(size_t)(m0 + r) * N + n] = f2bf(acc[nt][r] + bb);
    } else if constexpr (OUTMODE == 1) {
      float* o = (float*)OutP;
#pragma unroll
      for (int r = 0; r < 4; ++r)
        o[(size_t)(m0 + r) * N + n] = acc[nt][r] + bb;
    } else {
      // Vt[(b*16+h)*64 + d][s] ; m = (b,s), n = (h,d); 4 consecutive s -> 8B store
      unsigned short* o = (unsigned short*)OutP;
      const int b = m0 >> 10, s0 = m0 & 1023;
      const int hh = n >> 6, dd = n & 63;
      us4 pk;
#pragma unroll
      for (int r = 0; r < 4; ++r) pk[r] = f2bf(acc[nt][r] + bb);
      *reinterpret_cast<us4*>(&o[(size_t)((b * 16 + hh) * 64 + dd) * 1024 + s0]) = pk;
    }
  }
}

// Attention: grid (64 q-tiles, 64 bh), 256 threads (4 waves).
// Per WG: 16 q-rows, full S=1024 keys. Scores live in registers (16 x f32x4).
__global__ __launch_bounds__(256)
void attn_kernel(const unsigned short* __restrict__ Qb,
                 const unsigned short* __restrict__ Kb,
                 const unsigned short* __restrict__ Vt,
                 const int* __restrict__ mask,
                 unsigned short* __restrict__ ctx) {
  __shared__ unsigned short sP[16][1032];  // padded: stride 2064B, 16B-aligned
  __shared__ float redm[4][16];
  __shared__ float reds[4][16];
  const int bh = blockIdx.y, b = bh >> 4, h = bh & 15;
  const int q0 = blockIdx.x * 16;
  const int t = threadIdx.x;
  const int wave = t >> 6, lane = t & 63, lr = lane & 15, lg = lane >> 4;

  // Q fragments for this q-tile (rows lr, d-halves 0/32) — same for all waves
  const unsigned short* qp =
      Qb + (size_t)(b * 1024 + q0 + lr) * 1024 + h * 64 + lg * 8;
  const bf16x8 aq0 = ldbf8(qp);
  const bf16x8 aq1 = ldbf8(qp + 32);

  // Phase 1: scores for 16 k-tiles per wave, kept in registers
  f32x4 sc[16];
#pragma unroll
  for (int i = 0; i < 16; ++i) {
    const int kb = (wave + i * 4) * 16;
    const unsigned short* kp =
        Kb + (size_t)(b * 1024 + kb + lr) * 1024 + h * 64 + lg * 8;
    bf16x8 bk0 = ldbf8(kp);
    bf16x8 bk1 = ldbf8(kp + 32);
    f32x4 a = f32x4{0.f, 0.f, 0.f, 0.f};
    a = MFMA(aq0, bk0, a);
    a = MFMA(aq1, bk1, a);
    const int* mp = mask + (size_t)(b * 1024 + q0 + lg * 4) * 1024 + kb + lr;
#pragma unroll
    for (int r = 0; r < 4; ++r)
      a[r] = a[r] * 0.125f + (float)mp[r * 1024] * (-1e9f);
    sc[i] = a;
  }

  // Phase 2: softmax. Row q = lg*4+r; cols of this wave live in lanes sharing lg.
  float pm[4];
#pragma unroll
  for (int r = 0; r < 4; ++r) {
    pm[r] = -1e30f;
#pragma unroll
    for (int i = 0; i < 16; ++i) pm[r] = fmaxf(pm[r], sc[i][r]);
#pragma unroll
    for (int off = 1; off <= 8; off <<= 1)
      pm[r] = fmaxf(pm[r], __shfl_xor(pm[r], off));
  }
  if (lr == 0) {
#pragma unroll
    for (int r = 0; r < 4; ++r) redm[wave][lg * 4 + r] = pm[r];
  }
  __syncthreads();
  float fm[4], ps[4];
#pragma unroll
  for (int r = 0; r < 4; ++r) {
    const int row = lg * 4 + r;
    fm[r] = fmaxf(fmaxf(redm[0][row], redm[1][row]),
                  fmaxf(redm[2][row], redm[3][row]));
    ps[r] = 0.f;
  }
#pragma unroll
  for (int i = 0; i < 16; ++i) {
#pragma unroll
    for (int r = 0; r < 4; ++r) {
      float e = __expf(sc[i][r] - fm[r]);
      sc[i][r] = e;
      ps[r] += e;
    }
  }
#pragma unroll
  for (int r = 0; r < 4; ++r) {
#pragma unroll
    for (int off = 1; off <= 8; off <<= 1) ps[r] += __shfl_xor(ps[r], off);
  }
  if (lr == 0) {
#pragma unroll
    for (int r = 0; r < 4; ++r) reds[wave][lg * 4 + r] = ps[r];
  }
  __syncthreads();
  float inv[4];
#pragma unroll
  for (int r = 0; r < 4; ++r) {
    const int row = lg * 4 + r;
    inv[r] = 1.0f / (reds[0][row] + reds[1][row] + reds[2][row] + reds[3][row]);
  }
#pragma unroll
  for (int i = 0; i < 16; ++i) {
    const int kb = (wave + i * 4) * 16;
#pragma unroll
    for (int r = 0; r < 4; ++r)
      sP[lg * 4 + r][kb + lr] = f2bf(sc[i][r] * inv[r]);
  }
  __syncthreads();

  // Phase 3: PV. Wave handles d-tile wave*16; B-frag rows = Vt rows (contiguous).
  f32x4 oc = f32x4{0.f, 0.f, 0.f, 0.f};
  const unsigned short* vp =
      Vt + (size_t)(bh * 64 + wave * 16 + lr) * 1024 + lg * 8;
#pragma unroll
  for (int k0 = 0; k0 < 1024; k0 += 32) {
    bf16x8 ap = ldbf8(&sP[lr][k0 + lg * 8]);
    bf16x8 bv = ldbf8(vp + k0);
    oc = MFMA(ap, bv, oc);
  }
#pragma unroll
  for (int r = 0; r < 4; ++r)
    ctx[(size_t)(b * 1024 + q0 + lg * 4 + r) * 1024 + h * 64 + wave * 16 + lr] =
        f2bf(oc[r]);
}

extern "C" void kernel_launch(void* const* d_in, const int* in_sizes, int n_in,
                              void* d_out, int out_size, void* d_ws, size_t ws_size,
                              hipStream_t stream) {
  const float* query = (const float*)d_in[0];
  const float* key   = (const float*)d_in[1];
  const float* value = (const float*)d_in[2];
  const int*   mask  = (const int*)d_in[3];
  const float* wq = (const float*)d_in[4];
  const float* bq = (const float*)d_in[5];
  const float* wk = (const float*)d_in[6];
  const float* bk = (const float*)d_in[7];
  const float* wv = (const float*)d_in[8];
  const float* bv = (const float*)d_in[9];
  const float* wo = (const float*)d_in[10];
  const float* bo = (const float*)d_in[11];
  float* out = (float*)d_out;

  // ws layout (bf16 bits as ushort): Qb, Kb, Vt, ctx — 8 MB each = 32 MB total
  const size_t SZ = (size_t)4096 * 1024;
  unsigned short* Qb  = (unsigned short*)d_ws;
  unsigned short* Kb  = Qb + SZ;
  unsigned short* Vt  = Kb + SZ;
  unsigned short* ctx = Vt + SZ;

  dim3 gg(64, 16), blk(256);
  gemm_nt<float, 0><<<gg, blk, 0, stream>>>(query, wq, bq, Qb);
  gemm_nt<float, 0><<<gg, blk, 0, stream>>>(key, wk, bk, Kb);
  gemm_nt<float, 2><<<gg, blk, 0, stream>>>(value, wv, bv, Vt);
  attn_kernel<<<dim3(64, 64), blk, 0, stream>>>(Qb, Kb, Vt, mask, ctx);
  gemm_nt<unsigned short, 1><<<gg, blk, 0, stream>>>(ctx, wo, bo, out);
}

// Round 2
// 208.100 us; speedup vs baseline: 1.1447x; 1.1447x over previous
//
#include <hip/hip_runtime.h>
#include <hip/hip_bf16.h>

// MHA forward: B=4, S=1024, D=1024, H=16, DK=64.
// v2: dbuf T14 reg-staged 128x64 GEMMs; attn with LDS-staged K (swizzled glds),
// LDS mask bias, chunked swizzled P transpose.

typedef __bf16 bf16x8 __attribute__((ext_vector_type(8)));
typedef float f32x4 __attribute__((ext_vector_type(4)));
typedef unsigned short us8 __attribute__((ext_vector_type(8)));
typedef unsigned short us4 __attribute__((ext_vector_type(4)));

#define MFMA(a, b, c) __builtin_amdgcn_mfma_f32_16x16x32_bf16(a, b, c, 0, 0, 0)

__device__ __forceinline__ unsigned short f2b(float f) {
  return __builtin_bit_cast(unsigned short, __float2bfloat16(f));
}
__device__ __forceinline__ float b2f(unsigned short u) {
  return __builtin_bit_cast(float, (unsigned)u << 16);
}
__device__ __forceinline__ bf16x8 ldbf8(const unsigned short* p) {
  return __builtin_bit_cast(bf16x8, *reinterpret_cast<const us8*>(p));
}
__device__ __forceinline__ bf16x8 ldsbf8b(const unsigned short* base, int byteoff) {
  return __builtin_bit_cast(
      bf16x8, *reinterpret_cast<const us8*>(reinterpret_cast<const char*>(base) + byteoff));
}
__device__ __forceinline__ us8 cvt8(float4 a, float4 b) {
  us8 o;
  o[0] = f2b(a.x); o[1] = f2b(a.y); o[2] = f2b(a.z); o[3] = f2b(a.w);
  o[4] = f2b(b.x); o[5] = f2b(b.y); o[6] = f2b(b.z); o[7] = f2b(b.w);
  return o;
}
__device__ __forceinline__ void glds16(const void* g, void* l) {
  __builtin_amdgcn_global_load_lds(
      (const __attribute__((address_space(1))) unsigned int*)g,
      (__attribute__((address_space(3))) unsigned int*)l, 16, 0, 0);
}

// C[m][n] = sum_k A[m][k]*Bw[n][k] + bias[n]; M=4096, N=1024, K=1024.
// BM=128, BN=64, BK=64; 4 waves (2x2); double-buffered LDS; T14 reg-staging.
// OUTMODE: 0 = bf16 [M][N], 1 = f32 [M][N], 2 = bf16 head-transposed Vt[bh][d][s]
template <typename AT, int OUTMODE>
__global__ __launch_bounds__(256)
void gemm128(const AT* __restrict__ A, const float* __restrict__ Bw,
             const float* __restrict__ bias, void* __restrict__ OutP) {
  constexpr int K = 1024, N = 1024;
  constexpr bool ABF = (sizeof(AT) == 2);
  __shared__ __align__(16) unsigned short As[2][128 * 64];
  __shared__ __align__(16) unsigned short Bs[2][64 * 64];
  const int bm = blockIdx.x * 128, bn = blockIdx.y * 64;
  const int t = threadIdx.x;
  const int w = t >> 6, lane = t & 63, lr = lane & 15, lg = lane >> 4;
  const int wr = w >> 1, wc = w & 1;

  f32x4 acc[4][2];
#pragma unroll
  for (int m = 0; m < 4; ++m)
#pragma unroll
    for (int n = 0; n < 2; ++n) acc[m][n] = f32x4{0.f, 0.f, 0.f, 0.f};

  // prologue: stage k0=0 into buf 0
  {
#pragma unroll
    for (int it = 0; it < 4; ++it) {
      const int s = it * 256 + t, row = s >> 3, col = (s & 7) * 8;
      us8 v;
      if constexpr (ABF) {
        v = *reinterpret_cast<const us8*>(A + (size_t)(bm + row) * K + col);
      } else {
        const float4* p = reinterpret_cast<const float4*>(A + (size_t)(bm + row) * K + col);
        v = cvt8(p[0], p[1]);
      }
      *reinterpret_cast<us8*>(&As[0][s * 8]) = v;
    }
#pragma unroll
    for (int it = 0; it < 2; ++it) {
      const int s = it * 256 + t, row = s >> 3, col = (s & 7) * 8;
      const float4* p = reinterpret_cast<const float4*>(Bw + (size_t)(bn + row) * K + col);
      *reinterpret_cast<us8*>(&Bs[0][s * 8]) = cvt8(p[0], p[1]);
    }
  }
  __syncthreads();

  for (int c = 0; c < 16; ++c) {
    const int buf = c & 1;
    float4 raf[8];
    us8 rau[4];
    float4 rbf[4];
    if (c < 15) {  // T14: issue next-tile loads before compute
      const int k1 = (c + 1) * 64;
#pragma unroll
      for (int it = 0; it < 4; ++it) {
        const int s = it * 256 + t, row = s >> 3, col = (s & 7) * 8;
        if constexpr (ABF) {
          rau[it] = *reinterpret_cast<const us8*>(A + (size_t)(bm + row) * K + k1 + col);
        } else {
          const float4* p =
              reinterpret_cast<const float4*>(A + (size_t)(bm + row) * K + k1 + col);
          raf[2 * it] = p[0];
          raf[2 * it + 1] = p[1];
        }
      }
#pragma unroll
      for (int it = 0; it < 2; ++it) {
        const int s = it * 256 + t, row = s >> 3, col = (s & 7) * 8;
        const float4* p =
            reinterpret_cast<const float4*>(Bw + (size_t)(bn + row) * K + k1 + col);
        rbf[2 * it] = p[0];
        rbf[2 * it + 1] = p[1];
      }
    }
    // compute current tile
#pragma unroll
    for (int h2 = 0; h2 < 2; ++h2) {
      bf16x8 af[4], bfr[2];
#pragma unroll
      for (int m = 0; m < 4; ++m)
        af[m] = ldbf8(&As[buf][(wr * 64 + m * 16 + lr) * 64 + h2 * 32 + lg * 8]);
#pragma unroll
      for (int n = 0; n < 2; ++n)
        bfr[n] = ldbf8(&Bs[buf][(wc * 32 + n * 16 + lr) * 64 + h2 * 32 + lg * 8]);
#pragma unroll
      for (int m = 0; m < 4; ++m)
#pragma unroll
        for (int n = 0; n < 2; ++n) acc[m][n] = MFMA(af[m], bfr[n], acc[m][n]);
    }
    if (c < 15) {  // write-late: convert + ds_write after compute
#pragma unroll
      for (int it = 0; it < 4; ++it) {
        const int s = it * 256 + t;
        us8 v;
        if constexpr (ABF) v = rau[it];
        else v = cvt8(raf[2 * it], raf[2 * it + 1]);
        *reinterpret_cast<us8*>(&As[buf ^ 1][s * 8]) = v;
      }
#pragma unroll
      for (int it = 0; it < 2; ++it) {
        const int s = it * 256 + t;
        *reinterpret_cast<us8*>(&Bs[buf ^ 1][s * 8]) = cvt8(rbf[2 * it], rbf[2 * it + 1]);
      }
    }
    __syncthreads();
  }

#pragma unroll
  for (int m = 0; m < 4; ++m) {
    const int mr = bm + wr * 64 + m * 16 + lg * 4;
#pragma unroll
    for (int nt = 0; nt < 2; ++nt) {
      const int n = bn + wc * 32 + nt * 16 + lr;
      const float bb = bias[n];
      if constexpr (OUTMODE == 0) {
        unsigned short* o = (unsigned short*)OutP;
#pragma unroll
        for (int r = 0; r < 4; ++r) o[(size_t)(mr + r) * N + n] = f2b(acc[m][nt][r] + bb);
      } else if constexpr (OUTMODE == 1) {
        float* o = (float*)OutP;
#pragma unroll
        for (int r = 0; r < 4; ++r) o[(size_t)(mr + r) * N + n] = acc[m][nt][r] + bb;
      } else {
        unsigned short* o = (unsigned short*)OutP;
        const int b2 = mr >> 10, s0 = mr & 1023, hh = n >> 6, dd = n & 63;
        us4 pk;
#pragma unroll
        for (int r = 0; r < 4; ++r) pk[r] = f2b(acc[m][nt][r] + bb);
        *reinterpret_cast<us4*>(&o[(size_t)((b2 * 16 + hh) * 64 + dd) * 1024 + s0]) = pk;
      }
    }
  }
}

// Attention: grid (64 q-tiles, 64 bh), 256 threads (4 waves), 16 q-rows per WG.
// K staged via swizzled global_load_lds (dbuf); mask staged as bf16 bias in LDS;
// scores in regs; chunked swizzled P transpose for PV.
__global__ __launch_bounds__(256)
void attn_v2(const unsigned short* __restrict__ Qb,
             const unsigned short* __restrict__ Kb,
             const unsigned short* __restrict__ Vt,
             const int* __restrict__ mask,
             unsigned short* __restrict__ ctx) {
  __shared__ __align__(16) unsigned short Ks[2][128 * 64];  // 16KB each, XOR-swizzled
  __shared__ __align__(16) unsigned short Mb[2][16 * 136];  // bias bf16, padded
  __shared__ __align__(16) unsigned short sP[16 * 256];     // swizzled P, 8KB
  __shared__ float redm[4][16];
  __shared__ float reds[4][16];

  const int bh = blockIdx.y, b = bh >> 4, h = bh & 15;
  const int q0 = blockIdx.x * 16;
  const int t = threadIdx.x;
  const int w = t >> 6, lane = t & 63, lr = lane & 15, lg = lane >> 4;

  const unsigned short* qp = Qb + (size_t)(b * 1024 + q0 + lr) * 1024 + h * 64 + lg * 8;
  const bf16x8 aq0 = ldbf8(qp);
  const bf16x8 aq1 = ldbf8(qp + 32);

  const int mrow = t >> 4, mcol = (t & 15) * 8;
  const size_t mbase = (size_t)(b * 1024 + q0 + mrow) * 1024 + mcol;

  int4 mR0, mR1;
  auto loadMask = [&](int kc) {
    const int* mp = mask + mbase + kc * 128;
    mR0 = *reinterpret_cast<const int4*>(mp);
    mR1 = *reinterpret_cast<const int4*>(mp + 4);
  };
  auto writeMask = [&](int buf) {
    us8 o;
    o[0] = mR0.x ? 0xCE6Eu : 0u; o[1] = mR0.y ? 0xCE6Eu : 0u;  // bf16(-1e9)
    o[2] = mR0.z ? 0xCE6Eu : 0u; o[3] = mR0.w ? 0xCE6Eu : 0u;
    o[4] = mR1.x ? 0xCE6Eu : 0u; o[5] = mR1.y ? 0xCE6Eu : 0u;
    o[6] = mR1.z ? 0xCE6Eu : 0u; o[7] = mR1.w ? 0xCE6Eu : 0u;
    *reinterpret_cast<us8*>(&Mb[buf][mrow * 136 + mcol]) = o;
  };
  auto stageK = [&](int kc, int buf) {
    const int k0 = kc * 128;
#pragma unroll
    for (int it = 0; it < 4; ++it) {
      const int slot = it * 256 + t;
      const int r = slot >> 3;
      const int cb = (slot & 7) * 16;
      // pre-swizzled SOURCE + linear glds dest; read applies same XOR (rule #21)
      const char* g = (const char*)(Kb + (size_t)(b * 1024 + k0 + r) * 1024 + h * 64) +
                      (cb ^ ((r & 7) << 4));
      char* l = (char*)(&Ks[buf][0]) + (it * 256 + w * 64) * 16;  // wave-uniform base
      glds16(g, l);
    }
  };

  // ---- Phase 1: scores (8 chunks of 128 k, double-buffered) ----
  f32x4 sc[16];
  loadMask(0);
  stageK(0, 0);
  writeMask(0);
  __syncthreads();

#pragma unroll
  for (int c = 0; c < 8; ++c) {
    const int buf = c & 1;
    if (c < 7) {
      loadMask(c + 1);
      stageK(c + 1, buf ^ 1);
    }
#pragma unroll
    for (int j = 0; j < 2; ++j) {
      const int sloc = (w + 4 * j) * 16;
      const int r = sloc + lr;
      const int swz = (r & 7) << 4;
      bf16x8 bk0 = ldsbf8b(&Ks[buf][0], r * 128 + ((lg * 16) ^ swz));
      bf16x8 bk1 = ldsbf8b(&Ks[buf][0], r * 128 + ((lg * 16 + 64) ^ swz));
      f32x4 a = f32x4{0.f, 0.f, 0.f, 0.f};
      a = MFMA(aq0, bk0, a);
      a = MFMA(aq1, bk1, a);
#pragma unroll
      for (int r2 = 0; r2 < 4; ++r2) {
        float mb = b2f(Mb[buf][(lg * 4 + r2) * 136 + sloc + lr]);
        a[r2] = fmaf(a[r2], 0.125f, mb);
      }
      sc[c * 2 + j] = a;
    }
    if (c < 7) writeMask(buf ^ 1);
    __syncthreads();
  }

  // ---- Phase 2: softmax (rows q = lg*4+r; this wave holds 256 of 1024 cols) ----
  float pm[4];
#pragma unroll
  for (int r = 0; r < 4; ++r) {
    pm[r] = -1e30f;
#pragma unroll
    for (int i = 0; i < 16; ++i) pm[r] = fmaxf(pm[r], sc[i][r]);
#pragma unroll
    for (int off = 1; off <= 8; off <<= 1) pm[r] = fmaxf(pm[r], __shfl_xor(pm[r], off));
  }
  if (lr == 0) {
#pragma unroll
    for (int r = 0; r < 4; ++r) redm[w][lg * 4 + r] = pm[r];
  }
  __syncthreads();
  float fm[4], ps[4];
#pragma unroll
  for (int r = 0; r < 4; ++r) {
    const int row = lg * 4 + r;
    fm[r] = fmaxf(fmaxf(redm[0][row], redm[1][row]), fmaxf(redm[2][row], redm[3][row]));
    ps[r] = 0.f;
  }
#pragma unroll
  for (int i = 0; i < 16; ++i) {
#pragma unroll
    for (int r = 0; r < 4; ++r) {
      float e = __expf(sc[i][r] - fm[r]);
      sc[i][r] = e;
      ps[r] += e;
    }
  }
#pragma unroll
  for (int r = 0; r < 4; ++r) {
#pragma unroll
    for (int off = 1; off <= 8; off <<= 1) ps[r] += __shfl_xor(ps[r], off);
  }
  if (lr == 0) {
#pragma unroll
    for (int r = 0; r < 4; ++r) reds[w][lg * 4 + r] = ps[r];
  }
  __syncthreads();
  float inv[4];
#pragma unroll
  for (int r = 0; r < 4; ++r) {
    const int row = lg * 4 + r;
    inv[r] = 1.0f / (reds[0][row] + reds[1][row] + reds[2][row] + reds[3][row]);
  }

  // ---- Phase 3: PV in 4 chunks of 256 k (P via swizzled LDS transpose) ----
  f32x4 oc = f32x4{0.f, 0.f, 0.f, 0.f};
  const unsigned short* vp = Vt + (size_t)(bh * 64 + w * 16 + lr) * 1024 + lg * 8;
#pragma unroll
  for (int cc = 0; cc < 4; ++cc) {
#pragma unroll
    for (int t2 = 0; t2 < 4; ++t2) {
      const int i = cc * 4 + t2;
      const int s = 8 * (i >> 1) + w + 4 * (i & 1);
      const int lcol = s * 16 - cc * 256 + lr;  // 0..255 within chunk
#pragma unroll
      for (int r = 0; r < 4; ++r) {
        const int row = lg * 4 + r;
        const int idx = row * 256 + ((((lcol * 2) ^ ((row & 7) << 4))) >> 1);
        sP[idx] = f2b(sc[i][r] * inv[r]);
      }
    }
    __syncthreads();
#pragma unroll
    for (int kk = 0; kk < 8; ++kk) {
      bf16x8 ap = ldsbf8b(sP, lr * 512 + ((kk * 64 + lg * 16) ^ ((lr & 7) << 4)));
      bf16x8 bv = ldbf8(vp + cc * 256 + kk * 32);
      oc = MFMA(ap, bv, oc);
    }
    __syncthreads();
  }
#pragma unroll
  for (int r = 0; r < 4; ++r)
    ctx[(size_t)(b * 1024 + q0 + lg * 4 + r) * 1024 + h * 64 + w * 16 + lr] = f2b(oc[r]);
}

extern "C" void kernel_launch(void* const* d_in, const int* in_sizes, int n_in,
                              void* d_out, int out_size, void* d_ws, size_t ws_size,
                              hipStream_t stream) {
  const float* query = (const float*)d_in[0];
  const float* key   = (const float*)d_in[1];
  const float* value = (const float*)d_in[2];
  const int*   mask  = (const int*)d_in[3];
  const float* wq = (const float*)d_in[4];
  const float* bq = (const float*)d_in[5];
  const float* wk = (const float*)d_in[6];
  const float* bk = (const float*)d_in[7];
  const float* wv = (const float*)d_in[8];
  const float* bv = (const float*)d_in[9];
  const float* wo = (const float*)d_in[10];
  const float* bo = (const float*)d_in[11];
  float* out = (float*)d_out;

  // ws: Qb, Kb, Vt, ctx (bf16 bits) — 8 MB each = 32 MB
  const size_t SZ = (size_t)4096 * 1024;
  unsigned short* Qb  = (unsigned short*)d_ws;
  unsigned short* Kb  = Qb + SZ;
  unsigned short* Vt  = Kb + SZ;
  unsigned short* ctx = Vt + SZ;

  dim3 blk(256), gg(32, 16);
  gemm128<float, 0><<<gg, blk, 0, stream>>>(query, wq, bq, Qb);
  gemm128<float, 0><<<gg, blk, 0, stream>>>(key, wk, bk, Kb);
  gemm128<float, 2><<<gg, blk, 0, stream>>>(value, wv, bv, Vt);
  attn_v2<<<dim3(64, 64), blk, 0, stream>>>(Qb, Kb, Vt, mask, ctx);
  gemm128<unsigned short, 1><<<gg, blk, 0, stream>>>(ctx, wo, bo, out);
}

// Round 3
// 158.274 us; speedup vs baseline: 1.5051x; 1.3148x over previous
//
#include <hip/hip_runtime.h>
#include <hip/hip_bf16.h>

// MHA forward: B=4, S=1024, D=1024, H=16, DK=64.
// v3: fragment-major K/V/mask precompute -> barrier-free flash attention
// (online softmax, scores in regs, wave-private swizzled P transpose).

typedef __bf16 bf16x8 __attribute__((ext_vector_type(8)));
typedef float f32x4 __attribute__((ext_vector_type(4)));
typedef unsigned short us8 __attribute__((ext_vector_type(8)));
typedef unsigned short us4 __attribute__((ext_vector_type(4)));

#define MFMA(a, b, c) __builtin_amdgcn_mfma_f32_16x16x32_bf16(a, b, c, 0, 0, 0)

__device__ __forceinline__ unsigned short f2b(float f) {
  return __builtin_bit_cast(unsigned short, __float2bfloat16(f));
}
__device__ __forceinline__ float b2f(unsigned short u) {
  return __builtin_bit_cast(float, (unsigned)u << 16);
}
__device__ __forceinline__ bf16x8 ldbf8(const unsigned short* p) {
  return __builtin_bit_cast(bf16x8, *reinterpret_cast<const us8*>(p));
}
__device__ __forceinline__ bf16x8 ldsbf8b(const unsigned short* base, int byteoff) {
  return __builtin_bit_cast(
      bf16x8, *reinterpret_cast<const us8*>(reinterpret_cast<const char*>(base) + byteoff));
}
__device__ __forceinline__ us8 cvt8(float4 a, float4 b) {
  us8 o;
  o[0] = f2b(a.x); o[1] = f2b(a.y); o[2] = f2b(a.z); o[3] = f2b(a.w);
  o[4] = f2b(b.x); o[5] = f2b(b.y); o[6] = f2b(b.z); o[7] = f2b(b.w);
  return o;
}

// mask[b][q][k] (int 0/1) -> Mf in QK^T C-fragment order:
// Mf[((b*64+qt)*64+kt)*256 + lane*4 + r] = mask[b][qt*16+(lane>>4)*4+r][kt*16+(lane&15)] * bf16(-1e9)
__global__ __launch_bounds__(256)
void maskcvt(const int* __restrict__ mask, unsigned short* __restrict__ Mf) {
  const int idx = blockIdx.x * 256 + threadIdx.x;
  const int wl = idx & 63, tile = idx >> 6;
  const int kt = tile & 63, qt = (tile >> 6) & 63, b = tile >> 12;
  const int lr = wl & 15, lg = wl >> 4;
  const int* mp = mask + (size_t)(b * 1024 + qt * 16 + lg * 4) * 1024 + kt * 16 + lr;
  us4 o;
#pragma unroll
  for (int r = 0; r < 4; ++r) o[r] = mp[r * 1024] ? 0xCE6Eu : 0u;  // bf16(-1e9)
  *reinterpret_cast<us4*>(Mf + (size_t)idx * 4) = o;
}

// C[m][n] = sum_k A[m][k]*Bw[n][k] + bias[n]; M=4096, N=1024, K=1024.
// BM=128, BN=64, BK=64; 4 waves (2x2); double-buffered LDS; T14 reg-staging.
// OUTMODE: 0 = bf16 [M][N] (scaled by oscale)
//          1 = f32  [M][N]
//          2 = bf16 Vf fragment-major (PV B-operand)
//          3 = bf16 Kf fragment-major (QK^T B-operand)
template <typename AT, int OUTMODE>
__global__ __launch_bounds__(256)
void gemm128(const AT* __restrict__ A, const float* __restrict__ Bw,
             const float* __restrict__ bias, void* __restrict__ OutP, float oscale) {
  constexpr int K = 1024, N = 1024;
  constexpr bool ABF = (sizeof(AT) == 2);
  __shared__ __align__(16) unsigned short As[2][128 * 64];
  __shared__ __align__(16) unsigned short Bs[2][64 * 64];
  const int bm = blockIdx.x * 128, bn = blockIdx.y * 64;
  const int t = threadIdx.x;
  const int w = t >> 6, lane = t & 63, lr = lane & 15, lg = lane >> 4;
  const int wr = w >> 1, wc = w & 1;

  f32x4 acc[4][2];
#pragma unroll
  for (int m = 0; m < 4; ++m)
#pragma unroll
    for (int n = 0; n < 2; ++n) acc[m][n] = f32x4{0.f, 0.f, 0.f, 0.f};

  {
#pragma unroll
    for (int it = 0; it < 4; ++it) {
      const int s = it * 256 + t, row = s >> 3, col = (s & 7) * 8;
      us8 v;
      if constexpr (ABF) {
        v = *reinterpret_cast<const us8*>(A + (size_t)(bm + row) * K + col);
      } else {
        const float4* p = reinterpret_cast<const float4*>(A + (size_t)(bm + row) * K + col);
        v = cvt8(p[0], p[1]);
      }
      *reinterpret_cast<us8*>(&As[0][s * 8]) = v;
    }
#pragma unroll
    for (int it = 0; it < 2; ++it) {
      const int s = it * 256 + t, row = s >> 3, col = (s & 7) * 8;
      const float4* p = reinterpret_cast<const float4*>(Bw + (size_t)(bn + row) * K + col);
      *reinterpret_cast<us8*>(&Bs[0][s * 8]) = cvt8(p[0], p[1]);
    }
  }
  __syncthreads();

  for (int c = 0; c < 16; ++c) {
    const int buf = c & 1;
    float4 raf[8];
    us8 rau[4];
    float4 rbf[4];
    if (c < 15) {
      const int k1 = (c + 1) * 64;
#pragma unroll
      for (int it = 0; it < 4; ++it) {
        const int s = it * 256 + t, row = s >> 3, col = (s & 7) * 8;
        if constexpr (ABF) {
          rau[it] = *reinterpret_cast<const us8*>(A + (size_t)(bm + row) * K + k1 + col);
        } else {
          const float4* p =
              reinterpret_cast<const float4*>(A + (size_t)(bm + row) * K + k1 + col);
          raf[2 * it] = p[0];
          raf[2 * it + 1] = p[1];
        }
      }
#pragma unroll
      for (int it = 0; it < 2; ++it) {
        const int s = it * 256 + t, row = s >> 3, col = (s & 7) * 8;
        const float4* p =
            reinterpret_cast<const float4*>(Bw + (size_t)(bn + row) * K + k1 + col);
        rbf[2 * it] = p[0];
        rbf[2 * it + 1] = p[1];
      }
    }
#pragma unroll
    for (int h2 = 0; h2 < 2; ++h2) {
      bf16x8 af[4], bfr[2];
#pragma unroll
      for (int m = 0; m < 4; ++m)
        af[m] = ldbf8(&As[buf][(wr * 64 + m * 16 + lr) * 64 + h2 * 32 + lg * 8]);
#pragma unroll
      for (int n = 0; n < 2; ++n)
        bfr[n] = ldbf8(&Bs[buf][(wc * 32 + n * 16 + lr) * 64 + h2 * 32 + lg * 8]);
#pragma unroll
      for (int m = 0; m < 4; ++m)
#pragma unroll
        for (int n = 0; n < 2; ++n) acc[m][n] = MFMA(af[m], bfr[n], acc[m][n]);
    }
    if (c < 15) {
#pragma unroll
      for (int it = 0; it < 4; ++it) {
        const int s = it * 256 + t;
        us8 v;
        if constexpr (ABF) v = rau[it];
        else v = cvt8(raf[2 * it], raf[2 * it + 1]);
        *reinterpret_cast<us8*>(&As[buf ^ 1][s * 8]) = v;
      }
#pragma unroll
      for (int it = 0; it < 2; ++it) {
        const int s = it * 256 + t;
        *reinterpret_cast<us8*>(&Bs[buf ^ 1][s * 8]) = cvt8(rbf[2 * it], rbf[2 * it + 1]);
      }
    }
    __syncthreads();
  }

#pragma unroll
  for (int m = 0; m < 4; ++m) {
    const int mr = bm + wr * 64 + m * 16 + lg * 4;
#pragma unroll
    for (int nt = 0; nt < 2; ++nt) {
      const int n = bn + wc * 32 + nt * 16 + lr;
      const float bb = bias[n];
      if constexpr (OUTMODE == 0) {
        unsigned short* o = (unsigned short*)OutP;
#pragma unroll
        for (int r = 0; r < 4; ++r)
          o[(size_t)(mr + r) * N + n] = f2b((acc[m][nt][r] + bb) * oscale);
      } else if constexpr (OUTMODE == 1) {
        float* o = (float*)OutP;
#pragma unroll
        for (int r = 0; r < 4; ++r) o[(size_t)(mr + r) * N + n] = acc[m][nt][r] + bb;
      } else if constexpr (OUTMODE == 2) {
        // Vf: element V[bh][s][d] -> bh*65536 + (s>>5)*2048 + (d>>4)*512
        //     + ((d&15) | (((s>>3)&3)<<4))*8 + (s&7)
        unsigned short* o = (unsigned short*)OutP;
        const int b2 = mr >> 10, s0 = mr & 1023, hh = n >> 6, dd = n & 63;
        const size_t base = (size_t)(b2 * 16 + hh) * 65536 + (size_t)(s0 >> 5) * 2048 +
                            (size_t)(dd >> 4) * 512 +
                            (size_t)((dd & 15) | (((s0 >> 3) & 3) << 4)) * 8 + (s0 & 7);
        us4 pk;
#pragma unroll
        for (int r = 0; r < 4; ++r) pk[r] = f2b(acc[m][nt][r] + bb);
        *reinterpret_cast<us4*>(&o[base]) = pk;
      } else {
        // Kf: element K[bh][s][d] -> bh*65536 + (d>>5)*32768 + (s>>4)*512
        //     + (((s&15) | (((d>>3)&3)<<4)))*8 + (d&7)
        unsigned short* o = (unsigned short*)OutP;
        const int b2 = mr >> 10, s0 = mr & 1023, hh = n >> 6, dd = n & 63;
        const size_t base = (size_t)(b2 * 16 + hh) * 65536 + (size_t)(dd >> 5) * 32768 +
                            (size_t)(s0 >> 4) * 512 +
                            (size_t)((s0 & 15) | (((dd >> 3) & 3) << 4)) * 8 + (dd & 7);
#pragma unroll
        for (int r = 0; r < 4; ++r) o[base + r * 8] = f2b(acc[m][nt][r] + bb);
      }
    }
  }
}

// Flash attention, barrier-free. grid (64 bh, 8 qb), 256 threads = 4 waves.
// Each wave: 32 q-rows (2 sub-tiles of 16), online softmax over 16 KV chunks of 64.
__global__ __launch_bounds__(256)
void attn_v3(const unsigned short* __restrict__ Qb,
             const unsigned short* __restrict__ Kf,
             const unsigned short* __restrict__ Vf,
             const unsigned short* __restrict__ Mf,
             unsigned short* __restrict__ ctx) {
  __shared__ __align__(16) unsigned short sP[8][16 * 64];  // wave-private [w*2+qs]
  const int bh = blockIdx.x, b = bh >> 4, h = bh & 15;
  const int qb = blockIdx.y;
  const int t = threadIdx.x, w = t >> 6, wl = t & 63, lr = wl & 15, lg = wl >> 4;
  const int q0 = qb * 128 + w * 32;

  bf16x8 aq[2][2];
#pragma unroll
  for (int qs = 0; qs < 2; ++qs) {
    const unsigned short* qp =
        Qb + (size_t)(b * 1024 + q0 + qs * 16 + lr) * 1024 + h * 64 + lg * 8;
    aq[qs][0] = ldbf8(qp);
    aq[qs][1] = ldbf8(qp + 32);
  }
  const unsigned short* KfB = Kf + (size_t)bh * 65536;
  const unsigned short* VfB = Vf + (size_t)bh * 65536;
  const unsigned short* mf[2];
#pragma unroll
  for (int qs = 0; qs < 2; ++qs)
    mf[qs] = Mf + (size_t)((b * 64 + qb * 8 + w * 2 + qs) * 64) * 256 + wl * 4;

  f32x4 O[2][4];
  float m[2][4], l[2][4];
#pragma unroll
  for (int qs = 0; qs < 2; ++qs)
#pragma unroll
    for (int i = 0; i < 4; ++i) {
      O[qs][i] = f32x4{0.f, 0.f, 0.f, 0.f};
      m[qs][i] = -3e38f;
      l[qs][i] = 0.f;
    }

  unsigned short* spw0 = &sP[w * 2][0];
  unsigned short* spw1 = &sP[w * 2 + 1][0];

  for (int kc = 0; kc < 16; ++kc) {
    // ---- all chunk loads up front (V latency hides under QK^T + softmax) ----
    bf16x8 bk[4][2];
#pragma unroll
    for (int t4 = 0; t4 < 4; ++t4) {
      bk[t4][0] = ldbf8(KfB + (size_t)(kc * 4 + t4) * 512 + wl * 8);
      bk[t4][1] = ldbf8(KfB + 32768 + (size_t)(kc * 4 + t4) * 512 + wl * 8);
    }
    us4 mk[2][4];
#pragma unroll
    for (int qs = 0; qs < 2; ++qs)
#pragma unroll
      for (int t4 = 0; t4 < 4; ++t4)
        mk[qs][t4] = *reinterpret_cast<const us4*>(mf[qs] + (size_t)(kc * 4 + t4) * 256);
    bf16x8 bv[2][4];
#pragma unroll
    for (int ks = 0; ks < 2; ++ks)
#pragma unroll
      for (int dt = 0; dt < 4; ++dt)
        bv[ks][dt] = ldbf8(VfB + (size_t)(kc * 2 + ks) * 2048 + dt * 512 + wl * 8);

    // ---- QK^T + mask bias (Q pre-scaled by 1/8) ----
    f32x4 sc[2][4];
#pragma unroll
    for (int qs = 0; qs < 2; ++qs)
#pragma unroll
      for (int t4 = 0; t4 < 4; ++t4) {
        f32x4 a = f32x4{0.f, 0.f, 0.f, 0.f};
        a = MFMA(aq[qs][0], bk[t4][0], a);
        a = MFMA(aq[qs][1], bk[t4][1], a);
#pragma unroll
        for (int r = 0; r < 4; ++r) a[r] += b2f(mk[qs][t4][r]);
        sc[qs][t4] = a;
      }

    // ---- online softmax (rows wave-private; reduce over lr lanes) ----
#pragma unroll
    for (int qs = 0; qs < 2; ++qs) {
      float mc[4];
#pragma unroll
      for (int r = 0; r < 4; ++r)
        mc[r] = fmaxf(fmaxf(sc[qs][0][r], sc[qs][1][r]),
                      fmaxf(sc[qs][2][r], sc[qs][3][r]));
#pragma unroll
      for (int off = 1; off <= 8; off <<= 1)
#pragma unroll
        for (int r = 0; r < 4; ++r) mc[r] = fmaxf(mc[r], __shfl_xor(mc[r], off));
      bool sk = true;
#pragma unroll
      for (int r = 0; r < 4; ++r) sk = sk && (mc[r] <= m[qs][r] + 8.f);
      if (!__all(sk)) {  // T13 defer-rescale
#pragma unroll
        for (int r = 0; r < 4; ++r) {
          float mn = fmaxf(m[qs][r], mc[r]);
          float sf = __expf(m[qs][r] - mn);
          l[qs][r] *= sf;
#pragma unroll
          for (int dt = 0; dt < 4; ++dt) O[qs][dt][r] *= sf;
          m[qs][r] = mn;
        }
      }
      float ps[4] = {0.f, 0.f, 0.f, 0.f};
#pragma unroll
      for (int t4 = 0; t4 < 4; ++t4)
#pragma unroll
        for (int r = 0; r < 4; ++r) {
          float e = __expf(sc[qs][t4][r] - m[qs][r]);
          sc[qs][t4][r] = e;
          ps[r] += e;
        }
#pragma unroll
      for (int off = 1; off <= 8; off <<= 1)
#pragma unroll
        for (int r = 0; r < 4; ++r) ps[r] += __shfl_xor(ps[r], off);
#pragma unroll
      for (int r = 0; r < 4; ++r) l[qs][r] += ps[r];
      // P -> wave-private swizzled LDS (C-layout scatter; <=2-way conflicts)
      unsigned short* spw = qs ? spw1 : spw0;
#pragma unroll
      for (int t4 = 0; t4 < 4; ++t4)
#pragma unroll
        for (int r = 0; r < 4; ++r) {
          const int row = lg * 4 + r;
          const int bo = row * 128 + (((t4 * 16 + lr) * 2) ^ ((row & 7) << 4));
          *reinterpret_cast<unsigned short*>(reinterpret_cast<char*>(spw) + bo) =
              f2b(sc[qs][t4][r]);
        }
    }

    // ---- PV ----
#pragma unroll
    for (int ks = 0; ks < 2; ++ks) {
      const int abo = lr * 128 + ((ks * 64 + lg * 16) ^ ((lr & 7) << 4));
      bf16x8 apA = ldsbf8b(spw0, abo);
      bf16x8 apB = ldsbf8b(spw1, abo);
#pragma unroll
      for (int dt = 0; dt < 4; ++dt) {
        O[0][dt] = MFMA(apA, bv[ks][dt], O[0][dt]);
        O[1][dt] = MFMA(apB, bv[ks][dt], O[1][dt]);
      }
    }
  }

  // ---- epilogue: normalize + store ----
#pragma unroll
  for (int qs = 0; qs < 2; ++qs) {
    float inv[4];
#pragma unroll
    for (int r = 0; r < 4; ++r) inv[r] = 1.0f / l[qs][r];
#pragma unroll
    for (int dt = 0; dt < 4; ++dt)
#pragma unroll
      for (int r = 0; r < 4; ++r)
        ctx[(size_t)(b * 1024 + q0 + qs * 16 + lg * 4 + r) * 1024 + h * 64 + dt * 16 + lr] =
            f2b(O[qs][dt][r] * inv[r]);
  }
}

extern "C" void kernel_launch(void* const* d_in, const int* in_sizes, int n_in,
                              void* d_out, int out_size, void* d_ws, size_t ws_size,
                              hipStream_t stream) {
  const float* query = (const float*)d_in[0];
  const float* key   = (const float*)d_in[1];
  const float* value = (const float*)d_in[2];
  const int*   mask  = (const int*)d_in[3];
  const float* wq = (const float*)d_in[4];
  const float* bq = (const float*)d_in[5];
  const float* wk = (const float*)d_in[6];
  const float* bk = (const float*)d_in[7];
  const float* wv = (const float*)d_in[8];
  const float* bv = (const float*)d_in[9];
  const float* wo = (const float*)d_in[10];
  const float* bo = (const float*)d_in[11];
  float* out = (float*)d_out;

  // ws: Qb, Kf, Vf, ctx (bf16 bits) — 8 MB each = 32 MB.
  // Mask bias (frag-major, 8 MB) lives in d_out and is overwritten by the final GEMM.
  const size_t SZ = (size_t)4096 * 1024;
  unsigned short* Qb  = (unsigned short*)d_ws;
  unsigned short* Kf  = Qb + SZ;
  unsigned short* Vf  = Kf + SZ;
  unsigned short* ctx = Vf + SZ;
  unsigned short* Mf  = (unsigned short*)d_out;

  dim3 blk(256), gg(32, 16);
  maskcvt<<<4096, blk, 0, stream>>>(mask, Mf);
  gemm128<float, 0><<<gg, blk, 0, stream>>>(query, wq, bq, Qb, 0.125f);
  gemm128<float, 3><<<gg, blk, 0, stream>>>(key, wk, bk, Kf, 1.f);
  gemm128<float, 2><<<gg, blk, 0, stream>>>(value, wv, bv, Vf, 1.f);
  attn_v3<<<dim3(64, 8), blk, 0, stream>>>(Qb, Kf, Vf, Mf, ctx);
  gemm128<unsigned short, 1><<<gg, blk, 0, stream>>>(ctx, wo, bo, out, 1.f);
}

// Round 4
// 147.848 us; speedup vs baseline: 1.6113x; 1.0705x over previous
//
#include <hip/hip_runtime.h>
#include <hip/hip_bf16.h>

// MHA forward: B=4, S=1024, D=1024, H=16, DK=64.
// v4: swapped-QK^T flash attention (q lane-local -> 2-shfl reductions, mask as
// MFMA C-init, exp2 softmax, packed b64 P-writes); 128x128 XOR-swizzled GEMMs.

typedef __bf16 bf16x8 __attribute__((ext_vector_type(8)));
typedef float f32x4 __attribute__((ext_vector_type(4)));
typedef unsigned short us8 __attribute__((ext_vector_type(8)));
typedef unsigned short us4 __attribute__((ext_vector_type(4)));

#define MFMA(a, b, c) __builtin_amdgcn_mfma_f32_16x16x32_bf16(a, b, c, 0, 0, 0)
#define EXP2(x) __builtin_amdgcn_exp2f(x)

__device__ __forceinline__ unsigned short f2b(float f) {
  return __builtin_bit_cast(unsigned short, __float2bfloat16(f));
}
__device__ __forceinline__ float b2f(unsigned short u) {
  return __builtin_bit_cast(float, (unsigned)u << 16);
}
__device__ __forceinline__ bf16x8 ldbf8(const unsigned short* p) {
  return __builtin_bit_cast(bf16x8, *reinterpret_cast<const us8*>(p));
}
__device__ __forceinline__ us8 cvt8(float4 a, float4 b) {
  us8 o;
  o[0] = f2b(a.x); o[1] = f2b(a.y); o[2] = f2b(a.z); o[3] = f2b(a.w);
  o[4] = f2b(b.x); o[5] = f2b(b.y); o[6] = f2b(b.z); o[7] = f2b(b.w);
  return o;
}

// mask[b][q][k] -> Mf in *swapped* QK^T C-frag order (C[k][q], q=lane&15):
// Mf[((b*64+qt)*64+kt)*256 + wl*4 + r] = mask[b][qt*16+(wl&15)][kt*16+(wl>>4)*4+r]
//   * bf16(-1e9*log2e)  (0xCEAC)
__global__ __launch_bounds__(256)
void maskcvt(const int* __restrict__ mask, unsigned short* __restrict__ Mf) {
  const int idx = blockIdx.x * 256 + threadIdx.x;
  const int wl = idx & 63, tile = idx >> 6;
  const int kt = tile & 63, qt = (tile >> 6) & 63, b = tile >> 12;
  const int lr = wl & 15, lg = wl >> 4;
  const int4 mv = *reinterpret_cast<const int4*>(
      mask + (size_t)(b * 1024 + qt * 16 + lr) * 1024 + kt * 16 + lg * 4);
  us4 o;
  o[0] = mv.x ? 0xCEACu : 0u;
  o[1] = mv.y ? 0xCEACu : 0u;
  o[2] = mv.z ? 0xCEACu : 0u;
  o[3] = mv.w ? 0xCEACu : 0u;
  *reinterpret_cast<us4*>(Mf + (size_t)idx * 4) = o;
}

// C[m][n] = sum_k A[m][k]*Bw[n][k] + bias[n]; M=4096, N=K=1024.
// BM=BN=128, BK=64; 4 waves (2x2), 64x64 wave tiles (0.5 ds_read per MFMA);
// XOR-swizzled LDS; double-buffered; T14 reg-staging in 2 groups per K-step.
// OUTMODE: 0 = bf16 [M][N]*oscale, 1 = f32 [M][N], 2 = Vf frag-major, 3 = Kf frag-major
template <typename AT, int OUTMODE>
__global__ __launch_bounds__(256)
void gemm128(const AT* __restrict__ A, const float* __restrict__ Bw,
             const float* __restrict__ bias, void* __restrict__ OutP, float oscale) {
  constexpr int K = 1024, N = 1024;
  constexpr bool ABF = (sizeof(AT) == 2);
  __shared__ __align__(16) unsigned short As[2][128 * 64];
  __shared__ __align__(16) unsigned short Bs[2][128 * 64];
  const int bm = blockIdx.x * 128, bn = blockIdx.y * 128;
  const int t = threadIdx.x;
  const int w = t >> 6, lane = t & 63, lr = lane & 15, lg = lane >> 4;
  const int wr = w >> 1, wc = w & 1;
  const int srow_base = t >> 3;     // + it*32
  const int scolb = (t & 7) * 16;   // byte col in row

  f32x4 acc[4][4];
#pragma unroll
  for (int m = 0; m < 4; ++m)
#pragma unroll
    for (int n = 0; n < 4; ++n) acc[m][n] = f32x4{0.f, 0.f, 0.f, 0.f};

#define STROW(it) (srow_base + (it) * 32)
#define STA(buf, it, v)                                                          \
  *reinterpret_cast<us8*>((char*)&As[buf][0] + STROW(it) * 128 +                 \
                          (scolb ^ ((STROW(it) & 7) << 4))) = (v)
#define STB(buf, it, v)                                                          \
  *reinterpret_cast<us8*>((char*)&Bs[buf][0] + STROW(it) * 128 +                 \
                          (scolb ^ ((STROW(it) & 7) << 4))) = (v)

  // prologue: stage k0=0 into buf 0
  {
#pragma unroll
    for (int it = 0; it < 4; ++it) {
      const int row = STROW(it), col = (t & 7) * 8;
      us8 v;
      if constexpr (ABF) {
        v = *reinterpret_cast<const us8*>(A + (size_t)(bm + row) * K + col);
      } else {
        const float4* p = reinterpret_cast<const float4*>(A + (size_t)(bm + row) * K + col);
        v = cvt8(p[0], p[1]);
      }
      STA(0, it, v);
    }
#pragma unroll
    for (int it = 0; it < 4; ++it) {
      const int row = STROW(it), col = (t & 7) * 8;
      const float4* p = reinterpret_cast<const float4*>(Bw + (size_t)(bn + row) * K + col);
      STB(0, it, cvt8(p[0], p[1]));
    }
  }
  __syncthreads();

  const int swzc = (lr & 7) << 4;
  for (int c = 0; c < 16; ++c) {
    const int buf = c & 1;
    const int k1 = (c + 1) * 64;
    float4 fa[4], fb[4];
    us8 ua[2];
    // ---- group 0 loads (A slots 0-1, B slots 0-1) ----
    if (c < 15) {
#pragma unroll
      for (int it = 0; it < 2; ++it) {
        const int row = STROW(it), col = (t & 7) * 8;
        if constexpr (ABF) {
          ua[it] = *reinterpret_cast<const us8*>(A + (size_t)(bm + row) * K + k1 + col);
        } else {
          const float4* p =
              reinterpret_cast<const float4*>(A + (size_t)(bm + row) * K + k1 + col);
          fa[2 * it] = p[0];
          fa[2 * it + 1] = p[1];
        }
      }
#pragma unroll
      for (int it = 0; it < 2; ++it) {
        const int row = STROW(it), col = (t & 7) * 8;
        const float4* p =
            reinterpret_cast<const float4*>(Bw + (size_t)(bn + row) * K + k1 + col);
        fb[2 * it] = p[0];
        fb[2 * it + 1] = p[1];
      }
    }
    // ---- compute h2=0 ----
    {
      bf16x8 af[4], bfr[4];
#pragma unroll
      for (int m = 0; m < 4; ++m) {
        const int row = wr * 64 + m * 16 + lr;
        af[m] = ldbf8((const unsigned short*)((char*)&As[buf][0] + row * 128 +
                                              ((lg * 16) ^ swzc)));
      }
#pragma unroll
      for (int n = 0; n < 4; ++n) {
        const int row = wc * 64 + n * 16 + lr;
        bfr[n] = ldbf8((const unsigned short*)((char*)&Bs[buf][0] + row * 128 +
                                               ((lg * 16) ^ swzc)));
      }
#pragma unroll
      for (int m = 0; m < 4; ++m)
#pragma unroll
        for (int n = 0; n < 4; ++n) acc[m][n] = MFMA(af[m], bfr[n], acc[m][n]);
    }
    // ---- group 0 write + group 1 loads ----
    if (c < 15) {
#pragma unroll
      for (int it = 0; it < 2; ++it) {
        us8 v;
        if constexpr (ABF) v = ua[it];
        else v = cvt8(fa[2 * it], fa[2 * it + 1]);
        STA(buf ^ 1, it, v);
        STB(buf ^ 1, it, cvt8(fb[2 * it], fb[2 * it + 1]));
      }
#pragma unroll
      for (int it = 2; it < 4; ++it) {
        const int row = STROW(it), col = (t & 7) * 8;
        if constexpr (ABF) {
          ua[it - 2] = *reinterpret_cast<const us8*>(A + (size_t)(bm + row) * K + k1 + col);
        } else {
          const float4* p =
              reinterpret_cast<const float4*>(A + (size_t)(bm + row) * K + k1 + col);
          fa[2 * (it - 2)] = p[0];
          fa[2 * (it - 2) + 1] = p[1];
        }
      }
#pragma unroll
      for (int it = 2; it < 4; ++it) {
        const int row = STROW(it), col = (t & 7) * 8;
        const float4* p =
            reinterpret_cast<const float4*>(Bw + (size_t)(bn + row) * K + k1 + col);
        fb[2 * (it - 2)] = p[0];
        fb[2 * (it - 2) + 1] = p[1];
      }
    }
    // ---- compute h2=1 ----
    {
      bf16x8 af[4], bfr[4];
#pragma unroll
      for (int m = 0; m < 4; ++m) {
        const int row = wr * 64 + m * 16 + lr;
        af[m] = ldbf8((const unsigned short*)((char*)&As[buf][0] + row * 128 +
                                              ((64 + lg * 16) ^ swzc)));
      }
#pragma unroll
      for (int n = 0; n < 4; ++n) {
        const int row = wc * 64 + n * 16 + lr;
        bfr[n] = ldbf8((const unsigned short*)((char*)&Bs[buf][0] + row * 128 +
                                               ((64 + lg * 16) ^ swzc)));
      }
#pragma unroll
      for (int m = 0; m < 4; ++m)
#pragma unroll
        for (int n = 0; n < 4; ++n) acc[m][n] = MFMA(af[m], bfr[n], acc[m][n]);
    }
    // ---- group 1 write ----
    if (c < 15) {
#pragma unroll
      for (int it = 2; it < 4; ++it) {
        us8 v;
        if constexpr (ABF) v = ua[it - 2];
        else v = cvt8(fa[2 * (it - 2)], fa[2 * (it - 2) + 1]);
        STA(buf ^ 1, it, v);
        STB(buf ^ 1, it, cvt8(fb[2 * (it - 2)], fb[2 * (it - 2) + 1]));
      }
    }
    __syncthreads();
  }

#pragma unroll
  for (int m = 0; m < 4; ++m) {
    const int mr = bm + wr * 64 + m * 16 + lg * 4;
#pragma unroll
    for (int nt = 0; nt < 4; ++nt) {
      const int n = bn + wc * 64 + nt * 16 + lr;
      const float bb = bias[n];
      if constexpr (OUTMODE == 0) {
        unsigned short* o = (unsigned short*)OutP;
#pragma unroll
        for (int r = 0; r < 4; ++r)
          o[(size_t)(mr + r) * N + n] = f2b((acc[m][nt][r] + bb) * oscale);
      } else if constexpr (OUTMODE == 1) {
        float* o = (float*)OutP;
#pragma unroll
        for (int r = 0; r < 4; ++r) o[(size_t)(mr + r) * N + n] = acc[m][nt][r] + bb;
      } else if constexpr (OUTMODE == 2) {
        // Vf: V[bh][s][d] -> bh*65536 + (s>>5)*2048 + (d>>4)*512
        //     + ((d&15)|(((s>>3)&3)<<4))*8 + (s&7)
        unsigned short* o = (unsigned short*)OutP;
        const int b2 = mr >> 10, s0 = mr & 1023, hh = n >> 6, dd = n & 63;
        const size_t base = (size_t)(b2 * 16 + hh) * 65536 + (size_t)(s0 >> 5) * 2048 +
                            (size_t)(dd >> 4) * 512 +
                            (size_t)((dd & 15) | (((s0 >> 3) & 3) << 4)) * 8 + (s0 & 7);
        us4 pk;
#pragma unroll
        for (int r = 0; r < 4; ++r) pk[r] = f2b(acc[m][nt][r] + bb);
        *reinterpret_cast<us4*>(&o[base]) = pk;
      } else {
        // Kf: K[bh][s][d] -> bh*65536 + (d>>5)*32768 + (s>>4)*512
        //     + ((s&15)|(((d>>3)&3)<<4))*8 + (d&7)
        unsigned short* o = (unsigned short*)OutP;
        const int b2 = mr >> 10, s0 = mr & 1023, hh = n >> 6, dd = n & 63;
        const size_t base = (size_t)(b2 * 16 + hh) * 65536 + (size_t)(dd >> 5) * 32768 +
                            (size_t)(s0 >> 4) * 512 +
                            (size_t)((s0 & 15) | (((dd >> 3) & 3) << 4)) * 8 + (dd & 7);
#pragma unroll
        for (int r = 0; r < 4; ++r) o[base + r * 8] = f2b(acc[m][nt][r] + bb);
      }
    }
  }
#undef STROW
#undef STA
#undef STB
}

// Flash attention v4: swapped QK^T (q = lane&15 -> lane-local softmax state).
// grid (64 bh, 8 qb), 256 threads = 4 waves, 32 q-rows per wave.
__global__ __launch_bounds__(256)
void attn_v4(const unsigned short* __restrict__ Qb,
             const unsigned short* __restrict__ Kf,
             const unsigned short* __restrict__ Vf,
             const unsigned short* __restrict__ Mf,
             unsigned short* __restrict__ ctx) {
  __shared__ __align__(16) unsigned short sP[4][2][16 * 64];  // wave-private
  const int bh = blockIdx.x, b = bh >> 4, h = bh & 15;
  const int qb = blockIdx.y;
  const int t = threadIdx.x, w = t >> 6, wl = t & 63, lr = wl & 15, lg = wl >> 4;
  const int q0 = qb * 128 + w * 32;
  const int swz = (lr & 7) << 4;

  // Q as B-frag: lane holds Q[q=lr][d = lg*8..+7] per 32-d half
  bf16x8 bq[2][2];
#pragma unroll
  for (int qs = 0; qs < 2; ++qs) {
    const unsigned short* qp =
        Qb + (size_t)(b * 1024 + q0 + qs * 16 + lr) * 1024 + h * 64 + lg * 8;
    bq[qs][0] = ldbf8(qp);
    bq[qs][1] = ldbf8(qp + 32);
  }
  const unsigned short* KfB = Kf + (size_t)bh * 65536;
  const unsigned short* VfB = Vf + (size_t)bh * 65536;
  const unsigned short* mfp[2];
#pragma unroll
  for (int qs = 0; qs < 2; ++qs)
    mfp[qs] = Mf + (size_t)((b * 64 + qb * 8 + w * 2 + qs) * 64) * 256 + wl * 4;

  f32x4 O[2][4];
  float m_[2] = {-3e38f, -3e38f}, l_[2] = {0.f, 0.f};
#pragma unroll
  for (int qs = 0; qs < 2; ++qs)
#pragma unroll
    for (int dt = 0; dt < 4; ++dt) O[qs][dt] = f32x4{0.f, 0.f, 0.f, 0.f};

  unsigned short* sp[2] = {&sP[w][0][0], &sP[w][1][0]};

  for (int kc = 0; kc < 16; ++kc) {
    // ---- chunk loads (V latency hides under QK^T + softmax) ----
    bf16x8 ak[4][2];
#pragma unroll
    for (int t4 = 0; t4 < 4; ++t4) {
      ak[t4][0] = ldbf8(KfB + (size_t)(kc * 4 + t4) * 512 + wl * 8);
      ak[t4][1] = ldbf8(KfB + 32768 + (size_t)(kc * 4 + t4) * 512 + wl * 8);
    }
    us4 mk[2][4];
#pragma unroll
    for (int qs = 0; qs < 2; ++qs)
#pragma unroll
      for (int t4 = 0; t4 < 4; ++t4)
        mk[qs][t4] = *reinterpret_cast<const us4*>(mfp[qs] + (size_t)(kc * 4 + t4) * 256);
    bf16x8 bv[2][4];
#pragma unroll
    for (int ks = 0; ks < 2; ++ks)
#pragma unroll
      for (int dt = 0; dt < 4; ++dt)
        bv[ks][dt] = ldbf8(VfB + (size_t)(kc * 2 + ks) * 2048 + dt * 512 + wl * 8);

    // ---- QK^T with mask bias as C-init: sc[qs][t4][r] = S[q=lr][k=t4*16+lg*4+r] ----
    f32x4 sc[2][4];
#pragma unroll
    for (int qs = 0; qs < 2; ++qs)
#pragma unroll
      for (int t4 = 0; t4 < 4; ++t4) {
        f32x4 a;
#pragma unroll
        for (int r = 0; r < 4; ++r) a[r] = b2f(mk[qs][t4][r]);
        a = MFMA(ak[t4][0], bq[qs][0], a);
        a = MFMA(ak[t4][1], bq[qs][1], a);
        sc[qs][t4] = a;
      }

    // ---- online softmax (state lane-local at q=lr; reduce over lg via 2 shfl) ----
    float mc[2];
#pragma unroll
    for (int qs = 0; qs < 2; ++qs) {
      float v0 = fmaxf(fmaxf(sc[qs][0][0], sc[qs][0][1]),
                       fmaxf(sc[qs][0][2], sc[qs][0][3]));
      float v1 = fmaxf(fmaxf(sc[qs][1][0], sc[qs][1][1]),
                       fmaxf(sc[qs][1][2], sc[qs][1][3]));
      float v2 = fmaxf(fmaxf(sc[qs][2][0], sc[qs][2][1]),
                       fmaxf(sc[qs][2][2], sc[qs][2][3]));
      float v3 = fmaxf(fmaxf(sc[qs][3][0], sc[qs][3][1]),
                       fmaxf(sc[qs][3][2], sc[qs][3][3]));
      float v = fmaxf(fmaxf(v0, v1), fmaxf(v2, v3));
      v = fmaxf(v, __shfl_xor(v, 16));
      v = fmaxf(v, __shfl_xor(v, 32));
      mc[qs] = v;
    }
    const bool need = (mc[0] > m_[0] + 11.5f) || (mc[1] > m_[1] + 11.5f);
    if (__any(need)) {  // T13 defer-rescale (log2 units)
#pragma unroll
      for (int qs = 0; qs < 2; ++qs) {
        const float mn = fmaxf(m_[qs], mc[qs]);
        const float sf = EXP2(m_[qs] - mn);
        l_[qs] *= sf;
        m_[qs] = mn;
        float s4[4];
#pragma unroll
        for (int r = 0; r < 4; ++r) s4[r] = __shfl(sf, lg * 4 + r);
#pragma unroll
        for (int dt = 0; dt < 4; ++dt)
#pragma unroll
          for (int r = 0; r < 4; ++r) O[qs][dt][r] *= s4[r];
      }
    }
#pragma unroll
    for (int qs = 0; qs < 2; ++qs) {
      float ps = 0.f;
#pragma unroll
      for (int t4 = 0; t4 < 4; ++t4) {
        us4 pw;
#pragma unroll
        for (int r = 0; r < 4; ++r) {
          const float e = EXP2(sc[qs][t4][r] - m_[qs]);
          ps += e;
          pw[r] = f2b(e);
        }
        *reinterpret_cast<us4*>((char*)sp[qs] + lr * 128 + ((t4 * 32 + lg * 8) ^ swz)) = pw;
      }
      ps += __shfl_xor(ps, 16);
      ps += __shfl_xor(ps, 32);
      l_[qs] += ps;
    }

    // ---- PV: P as A-frag from wave-private LDS ----
#pragma unroll
    for (int ks = 0; ks < 2; ++ks) {
      const int off = lr * 128 + ((ks * 64 + lg * 16) ^ swz);
      bf16x8 apA = ldbf8((const unsigned short*)((char*)sp[0] + off));
      bf16x8 apB = ldbf8((const unsigned short*)((char*)sp[1] + off));
#pragma unroll
      for (int dt = 0; dt < 4; ++dt) {
        O[0][dt] = MFMA(apA, bv[ks][dt], O[0][dt]);
        O[1][dt] = MFMA(apB, bv[ks][dt], O[1][dt]);
      }
    }
  }

  // ---- epilogue: gather 1/l per O-row via shfl, normalize, store ----
#pragma unroll
  for (int qs = 0; qs < 2; ++qs) {
    float linv[4];
#pragma unroll
    for (int r = 0; r < 4; ++r) linv[r] = 1.0f / __shfl(l_[qs], lg * 4 + r);
#pragma unroll
    for (int dt = 0; dt < 4; ++dt)
#pragma unroll
      for (int r = 0; r < 4; ++r)
        ctx[(size_t)(b * 1024 + q0 + qs * 16 + lg * 4 + r) * 1024 + h * 64 + dt * 16 + lr] =
            f2b(O[qs][dt][r] * linv[r]);
  }
}

extern "C" void kernel_launch(void* const* d_in, const int* in_sizes, int n_in,
                              void* d_out, int out_size, void* d_ws, size_t ws_size,
                              hipStream_t stream) {
  const float* query = (const float*)d_in[0];
  const float* key   = (const float*)d_in[1];
  const float* value = (const float*)d_in[2];
  const int*   mask  = (const int*)d_in[3];
  const float* wq = (const float*)d_in[4];
  const float* bq = (const float*)d_in[5];
  const float* wk = (const float*)d_in[6];
  const float* bk = (const float*)d_in[7];
  const float* wv = (const float*)d_in[8];
  const float* bv = (const float*)d_in[9];
  const float* wo = (const float*)d_in[10];
  const float* bo = (const float*)d_in[11];
  float* out = (float*)d_out;

  // ws: Qb, Kf, Vf, ctx (bf16 bits) — 8 MB each = 32 MB.
  // Mf (frag-major mask bias, 8 MB) lives in d_out, overwritten by final GEMM.
  const size_t SZ = (size_t)4096 * 1024;
  unsigned short* Qb  = (unsigned short*)d_ws;
  unsigned short* Kf  = Qb + SZ;
  unsigned short* Vf  = Kf + SZ;
  unsigned short* ctx = Vf + SZ;
  unsigned short* Mf  = (unsigned short*)d_out;

  const float qscale = 0.125f * 1.4426950408889634f;  // 1/sqrt(64) * log2(e)
  dim3 blk(256), gg(32, 8);
  maskcvt<<<4096, blk, 0, stream>>>(mask, Mf);
  gemm128<float, 0><<<gg, blk, 0, stream>>>(query, wq, bq, Qb, qscale);
  gemm128<float, 3><<<gg, blk, 0, stream>>>(key, wk, bk, Kf, 1.f);
  gemm128<float, 2><<<gg, blk, 0, stream>>>(value, wv, bv, Vf, 1.f);
  attn_v4<<<dim3(64, 8), blk, 0, stream>>>(Qb, Kf, Vf, Mf, ctx);
  gemm128<unsigned short, 1><<<gg, blk, 0, stream>>>(ctx, wo, bo, out, 1.f);
}

// Round 5
// 134.957 us; speedup vs baseline: 1.7652x; 1.0955x over previous
//
#include <hip/hip_runtime.h>
#include <hip/hip_bf16.h>

// MHA forward: B=4, S=1024, D=1024, H=16, DK=64.
// v5: fused QKV projection GEMM (3 WG/CU), BM128xBN64 swizzled dbuf tiles;
// attn with 16 q-rows/wave (4 WG/CU) swapped-QK^T flash softmax.

typedef __bf16 bf16x8 __attribute__((ext_vector_type(8)));
typedef float f32x4 __attribute__((ext_vector_type(4)));
typedef unsigned short us8 __attribute__((ext_vector_type(8)));
typedef unsigned short us4 __attribute__((ext_vector_type(4)));

#define MFMA(a, b, c) __builtin_amdgcn_mfma_f32_16x16x32_bf16(a, b, c, 0, 0, 0)
#define EXP2(x) __builtin_amdgcn_exp2f(x)

__device__ __forceinline__ unsigned short f2b(float f) {
  return __builtin_bit_cast(unsigned short, __float2bfloat16(f));
}
__device__ __forceinline__ float b2f(unsigned short u) {
  return __builtin_bit_cast(float, (unsigned)u << 16);
}
__device__ __forceinline__ bf16x8 ldbf8(const unsigned short* p) {
  return __builtin_bit_cast(bf16x8, *reinterpret_cast<const us8*>(p));
}
__device__ __forceinline__ us8 cvt8(float4 a, float4 b) {
  us8 o;
  o[0] = f2b(a.x); o[1] = f2b(a.y); o[2] = f2b(a.z); o[3] = f2b(a.w);
  o[4] = f2b(b.x); o[5] = f2b(b.y); o[6] = f2b(b.z); o[7] = f2b(b.w);
  return o;
}

// mask[b][q][k] -> Mf in swapped QK^T C-frag order (C[k][q], q=lane&15):
// Mf[((b*64+qt)*64+kt)*256 + wl*4 + r] = mask[b][qt*16+(wl&15)][kt*16+(wl>>4)*4+r]
//   * bf16(-1e9*log2e) (0xCEAC)
__global__ __launch_bounds__(256)
void maskcvt(const int* __restrict__ mask, unsigned short* __restrict__ Mf) {
  const int idx = blockIdx.x * 256 + threadIdx.x;
  const int wl = idx & 63, tile = idx >> 6;
  const int kt = tile & 63, qt = (tile >> 6) & 63, b = tile >> 12;
  const int lr = wl & 15, lg = wl >> 4;
  const int4 mv = *reinterpret_cast<const int4*>(
      mask + (size_t)(b * 1024 + qt * 16 + lr) * 1024 + kt * 16 + lg * 4);
  us4 o;
  o[0] = mv.x ? 0xCEACu : 0u;
  o[1] = mv.y ? 0xCEACu : 0u;
  o[2] = mv.z ? 0xCEACu : 0u;
  o[3] = mv.w ? 0xCEACu : 0u;
  *reinterpret_cast<us4*>(Mf + (size_t)idx * 4) = o;
}

// ---------------- shared GEMM tile machinery (BM=128, BN=64, BK=64) ----------
// As: [128][64] bf16, Bs: [64][64] bf16, both XOR-swizzled rows (byte^((row&7)<<4)).
// 4 waves 2x2: wave tile 64x32; 6 ds_read_b128 per 8 MFMA, conflict-free.

#define GEMM_DECL                                                              \
  __shared__ __align__(16) unsigned short As[2][128 * 64];                     \
  __shared__ __align__(16) unsigned short Bs[2][64 * 64];                      \
  const int t = threadIdx.x;                                                   \
  const int w = t >> 6, lane = t & 63, lr = lane & 15, lg = lane >> 4;         \
  const int wr = w >> 1, wc = w & 1;                                           \
  const int srow = t >> 3;                                                     \
  const int scolb = (t & 7) * 16;                                              \
  const int scole = (t & 7) * 8;                                               \
  const int swzc = (lr & 7) << 4;

#define STA(buf, it, v)                                                        \
  *reinterpret_cast<us8*>((char*)&As[buf][0] + (srow + (it) * 32) * 128 +      \
                          (scolb ^ (((srow + (it) * 32) & 7) << 4))) = (v)
#define STB(buf, it, v)                                                        \
  *reinterpret_cast<us8*>((char*)&Bs[buf][0] + (srow + (it) * 32) * 128 +      \
                          (scolb ^ (((srow + (it) * 32) & 7) << 4))) = (v)

#define GEMM_COMPUTE_HALF(buf, h2)                                             \
  {                                                                            \
    bf16x8 af[4], bfr[2];                                                      \
    _Pragma("unroll") for (int m = 0; m < 4; ++m) {                            \
      const int row = wr * 64 + m * 16 + lr;                                   \
      af[m] = ldbf8((const unsigned short*)((char*)&As[buf][0] + row * 128 +   \
                                            (((h2) * 64 + lg * 16) ^ swzc)));  \
    }                                                                          \
    _Pragma("unroll") for (int n = 0; n < 2; ++n) {                            \
      const int row = wc * 32 + n * 16 + lr;                                   \
      bfr[n] = ldbf8((const unsigned short*)((char*)&Bs[buf][0] + row * 128 +  \
                                             (((h2) * 64 + lg * 16) ^ swzc))); \
    }                                                                          \
    _Pragma("unroll") for (int m = 0; m < 4; ++m)                              \
        _Pragma("unroll") for (int n = 0; n < 2; ++n)                          \
        acc[m][n] = MFMA(af[m], bfr[n], acc[m][n]);                            \
  }

// Fused QKV projection: z = blockIdx.z selects {query->Qb, key->Kf, value->Vf}.
__global__ __launch_bounds__(256)
void gemm_qkv(const float* __restrict__ Aq, const float* __restrict__ Akk,
              const float* __restrict__ Av, const float* __restrict__ Wq,
              const float* __restrict__ Wk, const float* __restrict__ Wv,
              const float* __restrict__ bq, const float* __restrict__ bk,
              const float* __restrict__ bv, unsigned short* __restrict__ Qb,
              unsigned short* __restrict__ Kf, unsigned short* __restrict__ Vf,
              float qscale) {
  constexpr int K = 1024, N = 1024;
  const int z = blockIdx.z;
  const float* A = (z == 0) ? Aq : (z == 1) ? Akk : Av;
  const float* Bw = (z == 0) ? Wq : (z == 1) ? Wk : Wv;
  const float* bias = (z == 0) ? bq : (z == 1) ? bk : bv;
  const int bm = blockIdx.x * 128, bn = blockIdx.y * 64;
  GEMM_DECL

  f32x4 acc[4][2];
#pragma unroll
  for (int m = 0; m < 4; ++m)
#pragma unroll
    for (int n = 0; n < 2; ++n) acc[m][n] = f32x4{0.f, 0.f, 0.f, 0.f};

  {
#pragma unroll
    for (int it = 0; it < 4; ++it) {
      const float4* p =
          reinterpret_cast<const float4*>(A + (size_t)(bm + srow + it * 32) * K + scole);
      STA(0, it, cvt8(p[0], p[1]));
    }
#pragma unroll
    for (int it = 0; it < 2; ++it) {
      const float4* p =
          reinterpret_cast<const float4*>(Bw + (size_t)(bn + srow + it * 32) * K + scole);
      STB(0, it, cvt8(p[0], p[1]));
    }
  }
  __syncthreads();

  for (int c = 0; c < 16; ++c) {
    const int buf = c & 1;
    float4 fa[8], fb[4];
    if (c < 15) {  // T14: issue next-tile loads first
      const int k1 = (c + 1) * 64;
#pragma unroll
      for (int it = 0; it < 4; ++it) {
        const float4* p = reinterpret_cast<const float4*>(
            A + (size_t)(bm + srow + it * 32) * K + k1 + scole);
        fa[2 * it] = p[0];
        fa[2 * it + 1] = p[1];
      }
#pragma unroll
      for (int it = 0; it < 2; ++it) {
        const float4* p = reinterpret_cast<const float4*>(
            Bw + (size_t)(bn + srow + it * 32) * K + k1 + scole);
        fb[2 * it] = p[0];
        fb[2 * it + 1] = p[1];
      }
    }
    GEMM_COMPUTE_HALF(buf, 0)
    GEMM_COMPUTE_HALF(buf, 1)
    if (c < 15) {  // write-late
#pragma unroll
      for (int it = 0; it < 4; ++it) STA(buf ^ 1, it, cvt8(fa[2 * it], fa[2 * it + 1]));
#pragma unroll
      for (int it = 0; it < 2; ++it) STB(buf ^ 1, it, cvt8(fb[2 * it], fb[2 * it + 1]));
    }
    __syncthreads();
  }

#pragma unroll
  for (int m = 0; m < 4; ++m) {
    const int mr = bm + wr * 64 + m * 16 + lg * 4;
#pragma unroll
    for (int nt = 0; nt < 2; ++nt) {
      const int n = bn + wc * 32 + nt * 16 + lr;
      const float bb = bias[n];
      if (z == 0) {
#pragma unroll
        for (int r = 0; r < 4; ++r)
          Qb[(size_t)(mr + r) * N + n] = f2b((acc[m][nt][r] + bb) * qscale);
      } else if (z == 1) {
        // Kf: K[bh][s][d] -> bh*65536 + (d>>5)*32768 + (s>>4)*512
        //     + ((s&15)|(((d>>3)&3)<<4))*8 + (d&7)
        const int b2 = mr >> 10, s0 = mr & 1023, hh = n >> 6, dd = n & 63;
        const size_t base = (size_t)(b2 * 16 + hh) * 65536 + (size_t)(dd >> 5) * 32768 +
                            (size_t)(s0 >> 4) * 512 +
                            (size_t)((s0 & 15) | (((dd >> 3) & 3) << 4)) * 8 + (dd & 7);
#pragma unroll
        for (int r = 0; r < 4; ++r) Kf[base + r * 8] = f2b(acc[m][nt][r] + bb);
      } else {
        // Vf: V[bh][s][d] -> bh*65536 + (s>>5)*2048 + (d>>4)*512
        //     + ((d&15)|(((s>>3)&3)<<4))*8 + (s&7)
        const int b2 = mr >> 10, s0 = mr & 1023, hh = n >> 6, dd = n & 63;
        const size_t base = (size_t)(b2 * 16 + hh) * 65536 + (size_t)(s0 >> 5) * 2048 +
                            (size_t)(dd >> 4) * 512 +
                            (size_t)((dd & 15) | (((s0 >> 3) & 3) << 4)) * 8 + (s0 & 7);
        us4 pk;
#pragma unroll
        for (int r = 0; r < 4; ++r) pk[r] = f2b(acc[m][nt][r] + bb);
        *reinterpret_cast<us4*>(&Vf[base]) = pk;
      }
    }
  }
}

// Output projection: A bf16 ctx, f32 out.
__global__ __launch_bounds__(256)
void gemm_out(const unsigned short* __restrict__ A, const float* __restrict__ Bw,
              const float* __restrict__ bias, float* __restrict__ Out) {
  constexpr int K = 1024, N = 1024;
  const int bm = blockIdx.x * 128, bn = blockIdx.y * 64;
  GEMM_DECL

  f32x4 acc[4][2];
#pragma unroll
  for (int m = 0; m < 4; ++m)
#pragma unroll
    for (int n = 0; n < 2; ++n) acc[m][n] = f32x4{0.f, 0.f, 0.f, 0.f};

  {
#pragma unroll
    for (int it = 0; it < 4; ++it)
      STA(0, it, *reinterpret_cast<const us8*>(A + (size_t)(bm + srow + it * 32) * K + scole));
#pragma unroll
    for (int it = 0; it < 2; ++it) {
      const float4* p =
          reinterpret_cast<const float4*>(Bw + (size_t)(bn + srow + it * 32) * K + scole);
      STB(0, it, cvt8(p[0], p[1]));
    }
  }
  __syncthreads();

  for (int c = 0; c < 16; ++c) {
    const int buf = c & 1;
    us8 ua[4];
    float4 fb[4];
    if (c < 15) {
      const int k1 = (c + 1) * 64;
#pragma unroll
      for (int it = 0; it < 4; ++it)
        ua[it] = *reinterpret_cast<const us8*>(A + (size_t)(bm + srow + it * 32) * K + k1 + scole);
#pragma unroll
      for (int it = 0; it < 2; ++it) {
        const float4* p = reinterpret_cast<const float4*>(
            Bw + (size_t)(bn + srow + it * 32) * K + k1 + scole);
        fb[2 * it] = p[0];
        fb[2 * it + 1] = p[1];
      }
    }
    GEMM_COMPUTE_HALF(buf, 0)
    GEMM_COMPUTE_HALF(buf, 1)
    if (c < 15) {
#pragma unroll
      for (int it = 0; it < 4; ++it) STA(buf ^ 1, it, ua[it]);
#pragma unroll
      for (int it = 0; it < 2; ++it) STB(buf ^ 1, it, cvt8(fb[2 * it], fb[2 * it + 1]));
    }
    __syncthreads();
  }

#pragma unroll
  for (int m = 0; m < 4; ++m) {
    const int mr = bm + wr * 64 + m * 16 + lg * 4;
#pragma unroll
    for (int nt = 0; nt < 2; ++nt) {
      const int n = bn + wc * 32 + nt * 16 + lr;
      const float bb = bias[n];
#pragma unroll
      for (int r = 0; r < 4; ++r) Out[(size_t)(mr + r) * N + n] = acc[m][nt][r] + bb;
    }
  }
}

// Flash attention v5: swapped QK^T, 16 q-rows per wave, 4 waves/WG.
// grid (64 bh, 16 qb) = 1024 WGs -> 4 WG/CU, 16 waves/CU.
__global__ __launch_bounds__(256)
void attn_v5(const unsigned short* __restrict__ Qb,
             const unsigned short* __restrict__ Kf,
             const unsigned short* __restrict__ Vf,
             const unsigned short* __restrict__ Mf,
             unsigned short* __restrict__ ctx) {
  __shared__ __align__(16) unsigned short sP[4][16 * 64];  // wave-private
  const int bh = blockIdx.x, b = bh >> 4, h = bh & 15;
  const int qb = blockIdx.y;
  const int t = threadIdx.x, w = t >> 6, wl = t & 63, lr = wl & 15, lg = wl >> 4;
  const int q0 = qb * 64 + w * 16;
  const int swz = (lr & 7) << 4;

  // Q as B-frag: lane holds Q[q=lr][d=lg*8..+7] per 32-d half
  const unsigned short* qp = Qb + (size_t)(b * 1024 + q0 + lr) * 1024 + h * 64 + lg * 8;
  const bf16x8 bq0 = ldbf8(qp);
  const bf16x8 bq1 = ldbf8(qp + 32);

  const unsigned short* KfB = Kf + (size_t)bh * 65536;
  const unsigned short* VfB = Vf + (size_t)bh * 65536;
  const unsigned short* mfp =
      Mf + (size_t)((b * 64 + qb * 4 + w) * 64) * 256 + wl * 4;

  f32x4 O[4];
  float m_ = -3e38f, l_ = 0.f;
#pragma unroll
  for (int dt = 0; dt < 4; ++dt) O[dt] = f32x4{0.f, 0.f, 0.f, 0.f};
  unsigned short* sp = &sP[w][0];

  for (int kc = 0; kc < 16; ++kc) {
    // ---- chunk loads (V consumed last; its latency hides under softmax) ----
    bf16x8 ak[4][2];
#pragma unroll
    for (int t4 = 0; t4 < 4; ++t4) {
      ak[t4][0] = ldbf8(KfB + (size_t)(kc * 4 + t4) * 512 + wl * 8);
      ak[t4][1] = ldbf8(KfB + 32768 + (size_t)(kc * 4 + t4) * 512 + wl * 8);
    }
    us4 mk[4];
#pragma unroll
    for (int t4 = 0; t4 < 4; ++t4)
      mk[t4] = *reinterpret_cast<const us4*>(mfp + (size_t)(kc * 4 + t4) * 256);
    bf16x8 bv[2][4];
#pragma unroll
    for (int ks = 0; ks < 2; ++ks)
#pragma unroll
      for (int dt = 0; dt < 4; ++dt)
        bv[ks][dt] = ldbf8(VfB + (size_t)(kc * 2 + ks) * 2048 + dt * 512 + wl * 8);

    // ---- QK^T with mask bias as C-init: sc[t4][r] = S[q=lr][k=t4*16+lg*4+r] ----
    f32x4 sc[4];
#pragma unroll
    for (int t4 = 0; t4 < 4; ++t4) {
      f32x4 a;
#pragma unroll
      for (int r = 0; r < 4; ++r) a[r] = b2f(mk[t4][r]);
      a = MFMA(ak[t4][0], bq0, a);
      a = MFMA(ak[t4][1], bq1, a);
      sc[t4] = a;
    }

    // ---- online softmax (state lane-local at q=lr; 2 shfl per reduction) ----
    float v0 = fmaxf(fmaxf(sc[0][0], sc[0][1]), fmaxf(sc[0][2], sc[0][3]));
    float v1 = fmaxf(fmaxf(sc[1][0], sc[1][1]), fmaxf(sc[1][2], sc[1][3]));
    float v2 = fmaxf(fmaxf(sc[2][0], sc[2][1]), fmaxf(sc[2][2], sc[2][3]));
    float v3 = fmaxf(fmaxf(sc[3][0], sc[3][1]), fmaxf(sc[3][2], sc[3][3]));
    float mc = fmaxf(fmaxf(v0, v1), fmaxf(v2, v3));
    mc = fmaxf(mc, __shfl_xor(mc, 16));
    mc = fmaxf(mc, __shfl_xor(mc, 32));
    if (__any(mc > m_ + 11.5f)) {  // T13 defer-rescale (log2 units)
      const float mn = fmaxf(m_, mc);
      const float sf = EXP2(m_ - mn);
      l_ *= sf;
      m_ = mn;
      float s4[4];
#pragma unroll
      for (int r = 0; r < 4; ++r) s4[r] = __shfl(sf, lg * 4 + r);
#pragma unroll
      for (int dt = 0; dt < 4; ++dt)
#pragma unroll
        for (int r = 0; r < 4; ++r) O[dt][r] *= s4[r];
    }
    float ps = 0.f;
#pragma unroll
    for (int t4 = 0; t4 < 4; ++t4) {
      us4 pw;
#pragma unroll
      for (int r = 0; r < 4; ++r) {
        const float e = EXP2(sc[t4][r] - m_);
        ps += e;
        pw[r] = f2b(e);
      }
      *reinterpret_cast<us4*>((char*)sp + lr * 128 + ((t4 * 32 + lg * 8) ^ swz)) = pw;
    }
    ps += __shfl_xor(ps, 16);
    ps += __shfl_xor(ps, 32);
    l_ += ps;

    // ---- PV: P as A-frag from wave-private LDS ----
#pragma unroll
    for (int ks = 0; ks < 2; ++ks) {
      bf16x8 ap =
          ldbf8((const unsigned short*)((char*)sp + lr * 128 + ((ks * 64 + lg * 16) ^ swz)));
#pragma unroll
      for (int dt = 0; dt < 4; ++dt) O[dt] = MFMA(ap, bv[ks][dt], O[dt]);
    }
  }

  // ---- epilogue: gather 1/l per O-row via shfl, normalize, store ----
  float linv[4];
#pragma unroll
  for (int r = 0; r < 4; ++r) linv[r] = 1.0f / __shfl(l_, lg * 4 + r);
#pragma unroll
  for (int dt = 0; dt < 4; ++dt)
#pragma unroll
    for (int r = 0; r < 4; ++r)
      ctx[(size_t)(b * 1024 + q0 + lg * 4 + r) * 1024 + h * 64 + dt * 16 + lr] =
          f2b(O[dt][r] * linv[r]);
}

extern "C" void kernel_launch(void* const* d_in, const int* in_sizes, int n_in,
                              void* d_out, int out_size, void* d_ws, size_t ws_size,
                              hipStream_t stream) {
  const float* query = (const float*)d_in[0];
  const float* key   = (const float*)d_in[1];
  const float* value = (const float*)d_in[2];
  const int*   mask  = (const int*)d_in[3];
  const float* wq = (const float*)d_in[4];
  const float* bq = (const float*)d_in[5];
  const float* wk = (const float*)d_in[6];
  const float* bk = (const float*)d_in[7];
  const float* wv = (const float*)d_in[8];
  const float* bv = (const float*)d_in[9];
  const float* wo = (const float*)d_in[10];
  const float* bo = (const float*)d_in[11];
  float* out = (float*)d_out;

  // ws: Qb, Kf, Vf, ctx (bf16 bits) — 8 MB each = 32 MB.
  // Mf (frag-major mask bias, 8 MB) lives in d_out, overwritten by final GEMM.
  const size_t SZ = (size_t)4096 * 1024;
  unsigned short* Qb  = (unsigned short*)d_ws;
  unsigned short* Kf  = Qb + SZ;
  unsigned short* Vf  = Kf + SZ;
  unsigned short* ctx = Vf + SZ;
  unsigned short* Mf  = (unsigned short*)d_out;

  const float qscale = 0.125f * 1.4426950408889634f;  // 1/sqrt(64) * log2(e)
  dim3 blk(256);
  maskcvt<<<4096, blk, 0, stream>>>(mask, Mf);
  gemm_qkv<<<dim3(32, 16, 3), blk, 0, stream>>>(query, key, value, wq, wk, wv,
                                                bq, bk, bv, Qb, Kf, Vf, qscale);
  attn_v5<<<dim3(64, 16), blk, 0, stream>>>(Qb, Kf, Vf, Mf, ctx);
  gemm_out<<<dim3(32, 16), blk, 0, stream>>>(ctx, wo, bo, out);
}